// Round 7
// baseline (166.502 us; speedup 1.0000x reference)
//
#include <hip/hip_runtime.h>

// MoE dense: N=16384, D=256, E=8, H=128.
// R7: BK=64 in all GEMM kernels (half the barriers, 2x MFMA per staged byte);
// stacked K padded 2080->2112 so stage2 runs 33 uniform BK=64 iters;
// gate restructured 256x64rows (1 block/CU!) -> 512x32rows.
// Workspace (80,314,368 B <= 80,437,248 known-OK):
//   xb   [16384][256] bf16 @ 0
//   w1t  [8][256][256] bf16 @ 8388608   (w1t[e][h][c] = W1[e][c][h])
//   wg1t [128][256] bf16 @ 9437184      (wg1t[h][c] = Wg1[c][h])
//   w2t  [256][2112] bf16 @ 9502720     (w2t[d][e*256+h]=W2[e][h][d]; 2048+e=b2; 2080+ = 0)
//   g    [16384][8] f32 @ 10584064
//   hw   [16384][2112] bf16 @ 11108352  (e*256+h = g*relu(.); 2048+e = g; 2056+ = 0)

typedef unsigned short USH;
typedef float f32x4 __attribute__((ext_vector_type(4)));
typedef __bf16 bf16x8 __attribute__((ext_vector_type(8)));

#define AS1 __attribute__((address_space(1)))
#define AS3 __attribute__((address_space(3)))

#define KS 2112   // stacked/padded K

__device__ __forceinline__ USH f2bf(float f) {
  unsigned int u = __float_as_uint(f);
  u += 0x7fffu + ((u >> 16) & 1u);   // RNE
  return (USH)(u >> 16);
}

__device__ __forceinline__ void gl2lds16(const void* g, void* l) {
  __builtin_amdgcn_global_load_lds((AS1 const void*)g, (AS3 void*)l, 16, 0, 0);
}

// ---------------- prep ----------------
// blocks: [0,2048) xb flat cast | [2048,2176) w1t-T | [2176,2184) wg1t-T |
// [2184,2312) w2t-T | 2312 w2t bias+zero cols

__global__ __launch_bounds__(256) void k_prep(
    const float* __restrict__ x,
    const float* __restrict__ Wg1,
    const float* __restrict__ W1,
    const float* __restrict__ W2,  const float* __restrict__ b2,
    USH* __restrict__ xb, USH* __restrict__ wg1t,
    USH* __restrict__ w1t, USH* __restrict__ w2t) {
  __shared__ float T[64][65];
  int b = blockIdx.x, tid = threadIdx.x;

  if (b < 2048) {               // xb: flat coalesced cast, 8 elems/thread
    size_t i8 = ((size_t)b * 256 + tid) * 8;
    float4 a = *(const float4*)(x + i8);
    float4 c = *(const float4*)(x + i8 + 4);
    USH v[8];
    v[0] = f2bf(a.x); v[1] = f2bf(a.y); v[2] = f2bf(a.z); v[3] = f2bf(a.w);
    v[4] = f2bf(c.x); v[5] = f2bf(c.y); v[6] = f2bf(c.z); v[7] = f2bf(c.w);
    *(uint4*)(xb + i8) = *(const uint4*)v;
  } else if (b < 2176) {        // w1t[e][h][c] = W1[e][c][h]
    int bp = b - 2048;
    int e = bp >> 4, tl = bp & 15;
    int c0 = (tl >> 2) * 64, h0 = (tl & 3) * 64;
    const float* src = W1 + (size_t)e * 65536;
#pragma unroll
    for (int p = 0; p < 4; ++p) {
      int r = p * 16 + (tid >> 4), d4 = (tid & 15) * 4;
      float4 v = *(const float4*)(src + (size_t)(c0 + r) * 256 + h0 + d4);
      T[r][d4] = v.x; T[r][d4 + 1] = v.y; T[r][d4 + 2] = v.z; T[r][d4 + 3] = v.w;
    }
    __syncthreads();
#pragma unroll
    for (int p = 0; p < 4; ++p) {
      int hr = p * 16 + (tid >> 4), c4 = (tid & 15) * 4;
      USH w[4];
#pragma unroll
      for (int j = 0; j < 4; ++j) w[j] = f2bf(T[c4 + j][hr]);
      *(uint2*)(w1t + (size_t)e * 65536 + (size_t)(h0 + hr) * 256 + c0 + c4) = *(const uint2*)w;
    }
  } else if (b < 2184) {        // wg1t[h][c] = Wg1[c][h]
    int bp = b - 2176;
    int c0 = (bp >> 1) * 64, h0 = (bp & 1) * 64;
#pragma unroll
    for (int p = 0; p < 4; ++p) {
      int r = p * 16 + (tid >> 4), d4 = (tid & 15) * 4;
      float4 v = *(const float4*)(Wg1 + (size_t)(c0 + r) * 128 + h0 + d4);
      T[r][d4] = v.x; T[r][d4 + 1] = v.y; T[r][d4 + 2] = v.z; T[r][d4 + 3] = v.w;
    }
    __syncthreads();
#pragma unroll
    for (int p = 0; p < 4; ++p) {
      int hr = p * 16 + (tid >> 4), c4 = (tid & 15) * 4;
      USH w[4];
#pragma unroll
      for (int j = 0; j < 4; ++j) w[j] = f2bf(T[c4 + j][hr]);
      *(uint2*)(wg1t + (size_t)(h0 + hr) * 256 + c0 + c4) = *(const uint2*)w;
    }
  } else if (b < 2312) {        // w2t[d][e*256+h] = W2[e][h][d]
    int bp = b - 2184;
    int e = bp >> 4, tl = bp & 15;
    int h0 = (tl >> 2) * 64, d0 = (tl & 3) * 64;
    const float* src = W2 + (size_t)e * 65536;
#pragma unroll
    for (int p = 0; p < 4; ++p) {
      int r = p * 16 + (tid >> 4), d4 = (tid & 15) * 4;
      float4 v = *(const float4*)(src + (size_t)(h0 + r) * 256 + d0 + d4);
      T[r][d4] = v.x; T[r][d4 + 1] = v.y; T[r][d4 + 2] = v.z; T[r][d4 + 3] = v.w;
    }
    __syncthreads();
#pragma unroll
    for (int p = 0; p < 4; ++p) {
      int dr = p * 16 + (tid >> 4), h4 = (tid & 15) * 4;
      USH w[4];
#pragma unroll
      for (int j = 0; j < 4; ++j) w[j] = f2bf(T[h4 + j][dr]);
      *(uint2*)(w2t + (size_t)(d0 + dr) * KS + e * 256 + h0 + h4) = *(const uint2*)w;
    }
  } else {                      // w2t cols 2048..2111: b2 then zeros (tid = d)
    size_t base = (size_t)tid * KS + 2048;
#pragma unroll
    for (int p = 0; p < 16; ++p) {
      USH w[4];
#pragma unroll
      for (int j = 0; j < 4; ++j) {
        int e = p * 4 + j;
        w[j] = (e < 8) ? f2bf(b2[e * 256 + tid]) : (USH)0;
      }
      *(uint2*)(w2t + base + p * 4) = *(const uint2*)w;
    }
  }
}

// ---------------- gate: g = softmax(relu(x@Wg1+bg1)@Wg2+bg2) ----------------
// R7: 512 blocks x 32 rows (was 256 x 64 = 1 block/CU), BK=64.

__global__ __launch_bounds__(256) void k_gate(const USH* __restrict__ xb,
                                              const USH* __restrict__ wg1t,
                                              const float* __restrict__ bg1,
                                              const float* __restrict__ wg2,
                                              const float* __restrict__ bg2,
                                              float* __restrict__ g,
                                              USH* __restrict__ hw) {
  __shared__ __align__(16) USH As[32 * 64];    // 4KB
  __shared__ __align__(16) USH Bs[128 * 64];   // 16KB
  __shared__ float hg[32 * 129];
  __shared__ float bg1s[128];
  __shared__ float w2s[128 * 8];
  __shared__ float b2s[8];
  __shared__ float lg[32 * 8];

  int tid = threadIdx.x;
  int wave = tid >> 6, lane = tid & 63;
  int quad = lane >> 4, l16 = lane & 15;
  int wr = wave >> 1, wc = wave & 1;
  int rowBase = blockIdx.x * 32;

  for (int t = tid; t < 1024; t += 256) w2s[t] = wg2[t];
  if (tid < 8) b2s[tid] = bg2[tid];
  if (tid < 128) bg1s[tid] = bg1[tid];

  f32x4 acc[4] = {};
  for (int kt = 0; kt < 4; ++kt) {
    int kb = kt * 64;
    {
      int r = tid >> 3, kc = (tid & 7) * 8;
      gl2lds16(xb + (size_t)(rowBase + r) * 256 + kb + kc, As + (size_t)tid * 8);
    }
#pragma unroll
    for (int c = 0; c < 4; ++c) {
      int i = c * 256 + tid;
      int r = i >> 3, kc = (i & 7) * 8;
      gl2lds16(wg1t + (size_t)r * 256 + kb + kc, Bs + (size_t)i * 8);
    }
    __syncthreads();
#pragma unroll
    for (int kk = 0; kk < 64; kk += 32) {
      bf16x8 av = *(const bf16x8*)(As + (wr * 16 + l16) * 64 + kk + quad * 8);
#pragma unroll
      for (int j = 0; j < 4; ++j) {
        bf16x8 bv = *(const bf16x8*)(Bs + (wc * 64 + j * 16 + l16) * 64 + kk + quad * 8);
        acc[j] = __builtin_amdgcn_mfma_f32_16x16x32_bf16(av, bv, acc[j], 0, 0, 0);
      }
    }
    __syncthreads();
  }

#pragma unroll
  for (int j = 0; j < 4; ++j)
#pragma unroll
    for (int r = 0; r < 4; ++r) {
      int row = wr * 16 + quad * 4 + r;
      int col = wc * 64 + j * 16 + l16;
      hg[row * 129 + col] = fmaxf(acc[j][r] + bg1s[col], 0.0f);
    }
  __syncthreads();

  {
    int row = tid >> 3, p = tid & 7;
    float s = b2s[p];
    for (int k = 0; k < 128; ++k) s += hg[row * 129 + k] * w2s[k * 8 + p];
    lg[row * 8 + p] = s;
  }
  __syncthreads();

  if (tid < 32) {
    float l[8];
    float m = -1e30f;
#pragma unroll
    for (int e = 0; e < 8; ++e) { l[e] = lg[tid * 8 + e]; m = fmaxf(m, l[e]); }
    float s = 0.0f;
#pragma unroll
    for (int e = 0; e < 8; ++e) { l[e] = expf(l[e] - m); s += l[e]; }
    float inv = 1.0f / s;
    size_t grow = rowBase + tid;
#pragma unroll
    for (int e = 0; e < 8; ++e) {
      float ge = l[e] * inv;
      g[grow * 8 + e] = ge;
      hw[grow * KS + 2048 + e] = f2bf(ge);
    }
#pragma unroll
    for (int z = 0; z < 56; ++z) hw[grow * KS + 2056 + z] = 0;
  }
}

// ---------------- stage 1: hw[:, e*256+h] = g[:,e]*relu(x@W1[e]+b1[e]) ------
// R7: BK=64 (4 iters, was 8).

__global__ __launch_bounds__(256) void k_stage1(const USH* __restrict__ xb,
                                                const USH* __restrict__ w1t,
                                                const float* __restrict__ b1,
                                                const float* __restrict__ g,
                                                USH* __restrict__ hw) {
  __shared__ __align__(16) USH As[128 * 64];   // 16KB
  __shared__ __align__(16) USH Bs[128 * 64];   // 16KB
  __shared__ float gs[128];
  __shared__ float b1s[128];

  int tid = threadIdx.x;
  int wave = tid >> 6, lane = tid & 63;
  int quad = lane >> 4, l16 = lane & 15;
  int wr = wave >> 1, wc = wave & 1;
  int rowBase = blockIdx.x * 128;
  int colBase = blockIdx.y * 128;
  int e = blockIdx.z;

  if (tid < 128) {
    gs[tid] = g[(size_t)(rowBase + tid) * 8 + e];
    b1s[tid] = b1[e * 256 + colBase + tid];
  }

  const USH* B = w1t + (size_t)e * 65536;

  f32x4 acc[4][4] = {};
  for (int kt = 0; kt < 4; ++kt) {
    int kb = kt * 64;
#pragma unroll
    for (int c = 0; c < 4; ++c) {
      int i = c * 256 + tid;
      int r = i >> 3, kc = (i & 7) * 8;
      gl2lds16(xb + (size_t)(rowBase + r) * 256 + kb + kc, As + (size_t)i * 8);
      gl2lds16(B + (size_t)(colBase + r) * 256 + kb + kc, Bs + (size_t)i * 8);
    }
    __syncthreads();
#pragma unroll
    for (int kk = 0; kk < 64; kk += 32) {
      bf16x8 av[4], bv[4];
#pragma unroll
      for (int i = 0; i < 4; ++i)
        av[i] = *(const bf16x8*)(As + (wr * 64 + i * 16 + l16) * 64 + kk + quad * 8);
#pragma unroll
      for (int j = 0; j < 4; ++j)
        bv[j] = *(const bf16x8*)(Bs + (wc * 64 + j * 16 + l16) * 64 + kk + quad * 8);
#pragma unroll
      for (int i = 0; i < 4; ++i)
#pragma unroll
        for (int j = 0; j < 4; ++j)
          acc[i][j] = __builtin_amdgcn_mfma_f32_16x16x32_bf16(av[i], bv[j], acc[i][j], 0, 0, 0);
    }
    __syncthreads();
  }

#pragma unroll
  for (int i = 0; i < 4; ++i) {
#pragma unroll
    for (int r = 0; r < 4; ++r) {
      int rl = wr * 64 + i * 16 + quad * 4 + r;
      float gg = gs[rl];
      size_t grow = (size_t)(rowBase + rl);
#pragma unroll
      for (int j = 0; j < 4; ++j) {
        int cl = wc * 64 + j * 16 + l16;
        float v = fmaxf(acc[i][j][r] + b1s[cl], 0.0f) * gg;
        hw[grow * KS + e * 256 + colBase + cl] = f2bf(v);
      }
    }
  }
}

// ---------------- stage 2: out = hw @ w2t^T (K=2112, zero-padded) -----------
// 64x64 tiles, 1024 blocks = 4/CU, BK=64 -> 33 iters (was 65).

__global__ __launch_bounds__(256) void k_stage2(const USH* __restrict__ hwm,
                                                const USH* __restrict__ w2t,
                                                float* __restrict__ out) {
  __shared__ __align__(16) USH As[64 * 64];    // 8KB
  __shared__ __align__(16) USH Bs[64 * 64];    // 8KB

  int tid = threadIdx.x;
  int wave = tid >> 6, lane = tid & 63;
  int quad = lane >> 4, l16 = lane & 15;
  int rowBase = blockIdx.x * 64;
  int colBase = blockIdx.y * 64;

  f32x4 acc[4] = {};
  for (int kt = 0; kt < 33; ++kt) {
    int kb = kt * 64;
#pragma unroll
    for (int c = 0; c < 2; ++c) {
      int i = c * 256 + tid;
      int r = i >> 3, kc = (i & 7) * 8;
      gl2lds16(hwm + (size_t)(rowBase + r) * KS + kb + kc, As + (size_t)i * 8);
      gl2lds16(w2t + (size_t)(colBase + r) * KS + kb + kc, Bs + (size_t)i * 8);
    }
    __syncthreads();
#pragma unroll
    for (int kk = 0; kk < 64; kk += 32) {
      bf16x8 av = *(const bf16x8*)(As + (wave * 16 + l16) * 64 + kk + quad * 8);
#pragma unroll
      for (int j = 0; j < 4; ++j) {
        bf16x8 bv = *(const bf16x8*)(Bs + (j * 16 + l16) * 64 + kk + quad * 8);
        acc[j] = __builtin_amdgcn_mfma_f32_16x16x32_bf16(av, bv, acc[j], 0, 0, 0);
      }
    }
    __syncthreads();
  }

#pragma unroll
  for (int j = 0; j < 4; ++j)
#pragma unroll
    for (int r = 0; r < 4; ++r) {
      int row = wave * 16 + quad * 4 + r;
      out[(size_t)(rowBase + row) * 256 + colBase + j * 16 + l16] = acc[j][r];
    }
}

// ---------------- launch ----------------

extern "C" void kernel_launch(void* const* d_in, const int* in_sizes, int n_in,
                              void* d_out, int out_size, void* d_ws, size_t ws_size,
                              hipStream_t stream) {
  const float* x   = (const float*)d_in[0];
  const float* Wg1 = (const float*)d_in[1];
  const float* bg1 = (const float*)d_in[2];
  const float* Wg2 = (const float*)d_in[3];
  const float* bg2 = (const float*)d_in[4];
  const float* W1  = (const float*)d_in[5];
  const float* b1  = (const float*)d_in[6];
  const float* W2  = (const float*)d_in[7];
  const float* b2  = (const float*)d_in[8];
  float* out = (float*)d_out;

  char* ws = (char*)d_ws;
  USH*   xb   = (USH*)(ws);
  USH*   w1t  = (USH*)(ws + 8388608);
  USH*   wg1t = (USH*)(ws + 9437184);
  USH*   w2t  = (USH*)(ws + 9502720);
  float* g    = (float*)(ws + 10584064);
  USH*   hw   = (USH*)(ws + 11108352);   // total 80,314,368 B

  hipLaunchKernelGGL(k_prep, dim3(2313), dim3(256), 0, stream,
                     x, Wg1, W1, W2, b2, xb, wg1t, w1t, w2t);
  hipLaunchKernelGGL(k_gate,   dim3(512),       dim3(256), 0, stream, xb, wg1t, bg1, Wg2, bg2, g, hw);
  hipLaunchKernelGGL(k_stage1, dim3(128, 2, 8), dim3(256), 0, stream, xb, w1t, b1, g, hw);
  hipLaunchKernelGGL(k_stage2, dim3(256, 4),    dim3(256), 0, stream, hw, w2t, out);
}

// Round 8
// 148.089 us; speedup vs baseline: 1.1243x; 1.1243x over previous
//
#include <hip/hip_runtime.h>

// MoE dense: N=16384, D=256, E=8, H=128.
// R8: XOR-swizzled LDS tiles. R7's BK=64 gave 128B row stride = 32 banks ->
// row term drops out of bank index -> ~16-way conflicts on every frag read
// (SQ_LDS_BANK_CONFLICT 5.3M->16.2M, stage2 43->48us). Fix: chunk c of row r
// stored at slot c^(r&7); global_load_lds-compatible (only the global source
// chunk index is permuted). Frag reads now spread 8 chunk positions -> 2
// lanes/bank = free (m136).
// Workspace (80,314,368 B):
//   xb   [16384][256] bf16 @ 0
//   w1t  [8][256][256] bf16 @ 8388608   (w1t[e][h][c] = W1[e][c][h])
//   wg1t [128][256] bf16 @ 9437184      (wg1t[h][c] = Wg1[c][h])
//   w2t  [256][2112] bf16 @ 9502720     (w2t[d][e*256+h]=W2[e][h][d]; 2048+e=b2; 2080+=0)
//   g    [16384][8] f32 @ 10584064
//   hw   [16384][2112] bf16 @ 11108352  (e*256+h = g*relu(.); 2048+e = g; 2056+=0)

typedef unsigned short USH;
typedef float f32x4 __attribute__((ext_vector_type(4)));
typedef __bf16 bf16x8 __attribute__((ext_vector_type(8)));

#define AS1 __attribute__((address_space(1)))
#define AS3 __attribute__((address_space(3)))

#define KS 2112   // stacked/padded K

__device__ __forceinline__ USH f2bf(float f) {
  unsigned int u = __float_as_uint(f);
  u += 0x7fffu + ((u >> 16) & 1u);   // RNE
  return (USH)(u >> 16);
}

__device__ __forceinline__ void gl2lds16(const void* g, void* l) {
  __builtin_amdgcn_global_load_lds((AS1 const void*)g, (AS3 void*)l, 16, 0, 0);
}

// ---------------- prep (unchanged from R7) ----------------

__global__ __launch_bounds__(256) void k_prep(
    const float* __restrict__ x,
    const float* __restrict__ Wg1,
    const float* __restrict__ W1,
    const float* __restrict__ W2,  const float* __restrict__ b2,
    USH* __restrict__ xb, USH* __restrict__ wg1t,
    USH* __restrict__ w1t, USH* __restrict__ w2t) {
  __shared__ float T[64][65];
  int b = blockIdx.x, tid = threadIdx.x;

  if (b < 2048) {               // xb: flat coalesced cast
    size_t i8 = ((size_t)b * 256 + tid) * 8;
    float4 a = *(const float4*)(x + i8);
    float4 c = *(const float4*)(x + i8 + 4);
    USH v[8];
    v[0] = f2bf(a.x); v[1] = f2bf(a.y); v[2] = f2bf(a.z); v[3] = f2bf(a.w);
    v[4] = f2bf(c.x); v[5] = f2bf(c.y); v[6] = f2bf(c.z); v[7] = f2bf(c.w);
    *(uint4*)(xb + i8) = *(const uint4*)v;
  } else if (b < 2176) {        // w1t[e][h][c] = W1[e][c][h]
    int bp = b - 2048;
    int e = bp >> 4, tl = bp & 15;
    int c0 = (tl >> 2) * 64, h0 = (tl & 3) * 64;
    const float* src = W1 + (size_t)e * 65536;
#pragma unroll
    for (int p = 0; p < 4; ++p) {
      int r = p * 16 + (tid >> 4), d4 = (tid & 15) * 4;
      float4 v = *(const float4*)(src + (size_t)(c0 + r) * 256 + h0 + d4);
      T[r][d4] = v.x; T[r][d4 + 1] = v.y; T[r][d4 + 2] = v.z; T[r][d4 + 3] = v.w;
    }
    __syncthreads();
#pragma unroll
    for (int p = 0; p < 4; ++p) {
      int hr = p * 16 + (tid >> 4), c4 = (tid & 15) * 4;
      USH w[4];
#pragma unroll
      for (int j = 0; j < 4; ++j) w[j] = f2bf(T[c4 + j][hr]);
      *(uint2*)(w1t + (size_t)e * 65536 + (size_t)(h0 + hr) * 256 + c0 + c4) = *(const uint2*)w;
    }
  } else if (b < 2184) {        // wg1t[h][c] = Wg1[c][h]
    int bp = b - 2176;
    int c0 = (bp >> 1) * 64, h0 = (bp & 1) * 64;
#pragma unroll
    for (int p = 0; p < 4; ++p) {
      int r = p * 16 + (tid >> 4), d4 = (tid & 15) * 4;
      float4 v = *(const float4*)(Wg1 + (size_t)(c0 + r) * 128 + h0 + d4);
      T[r][d4] = v.x; T[r][d4 + 1] = v.y; T[r][d4 + 2] = v.z; T[r][d4 + 3] = v.w;
    }
    __syncthreads();
#pragma unroll
    for (int p = 0; p < 4; ++p) {
      int hr = p * 16 + (tid >> 4), c4 = (tid & 15) * 4;
      USH w[4];
#pragma unroll
      for (int j = 0; j < 4; ++j) w[j] = f2bf(T[c4 + j][hr]);
      *(uint2*)(wg1t + (size_t)(h0 + hr) * 256 + c0 + c4) = *(const uint2*)w;
    }
  } else if (b < 2312) {        // w2t[d][e*256+h] = W2[e][h][d]
    int bp = b - 2184;
    int e = bp >> 4, tl = bp & 15;
    int h0 = (tl >> 2) * 64, d0 = (tl & 3) * 64;
    const float* src = W2 + (size_t)e * 65536;
#pragma unroll
    for (int p = 0; p < 4; ++p) {
      int r = p * 16 + (tid >> 4), d4 = (tid & 15) * 4;
      float4 v = *(const float4*)(src + (size_t)(h0 + r) * 256 + d0 + d4);
      T[r][d4] = v.x; T[r][d4 + 1] = v.y; T[r][d4 + 2] = v.z; T[r][d4 + 3] = v.w;
    }
    __syncthreads();
#pragma unroll
    for (int p = 0; p < 4; ++p) {
      int dr = p * 16 + (tid >> 4), h4 = (tid & 15) * 4;
      USH w[4];
#pragma unroll
      for (int j = 0; j < 4; ++j) w[j] = f2bf(T[h4 + j][dr]);
      *(uint2*)(w2t + (size_t)(d0 + dr) * KS + e * 256 + h0 + h4) = *(const uint2*)w;
    }
  } else {                      // w2t cols 2048..2111: b2 then zeros
    size_t base = (size_t)tid * KS + 2048;
#pragma unroll
    for (int p = 0; p < 16; ++p) {
      USH w[4];
#pragma unroll
      for (int j = 0; j < 4; ++j) {
        int e = p * 4 + j;
        w[j] = (e < 8) ? f2bf(b2[e * 256 + tid]) : (USH)0;
      }
      *(uint2*)(w2t + base + p * 4) = *(const uint2*)w;
    }
  }
}

// ---------------- gate (512 blocks x 32 rows, BK=64, swizzled) ----------------

__global__ __launch_bounds__(256) void k_gate(const USH* __restrict__ xb,
                                              const USH* __restrict__ wg1t,
                                              const float* __restrict__ bg1,
                                              const float* __restrict__ wg2,
                                              const float* __restrict__ bg2,
                                              float* __restrict__ g,
                                              USH* __restrict__ hw) {
  __shared__ __align__(16) USH As[32 * 64];    // 4KB, swizzled
  __shared__ __align__(16) USH Bs[128 * 64];   // 16KB, swizzled
  __shared__ float hg[32 * 129];
  __shared__ float bg1s[128];
  __shared__ float w2s[128 * 8];
  __shared__ float b2s[8];
  __shared__ float lg[32 * 8];

  int tid = threadIdx.x;
  int wave = tid >> 6, lane = tid & 63;
  int quad = lane >> 4, l16 = lane & 15;
  int sw = l16 & 7;                            // read-side swizzle
  int wr = wave >> 1, wc = wave & 1;
  int rowBase = blockIdx.x * 32;

  for (int t = tid; t < 1024; t += 256) w2s[t] = wg2[t];
  if (tid < 8) b2s[tid] = bg2[tid];
  if (tid < 128) bg1s[tid] = bg1[tid];

  f32x4 acc[4] = {};
  for (int kt = 0; kt < 4; ++kt) {
    int kb = kt * 64;
    {
      int r = tid >> 3, c8 = (tid & 7) ^ (r & 7);
      gl2lds16(xb + (size_t)(rowBase + r) * 256 + kb + c8 * 8, As + (size_t)tid * 8);
    }
#pragma unroll
    for (int c = 0; c < 4; ++c) {
      int i = c * 256 + tid;
      int r = i >> 3, c8 = (i & 7) ^ (r & 7);
      gl2lds16(wg1t + (size_t)r * 256 + kb + c8 * 8, Bs + (size_t)i * 8);
    }
    __syncthreads();
#pragma unroll
    for (int kkc = 0; kkc < 8; kkc += 4) {
      bf16x8 av = *(const bf16x8*)(As + (wr * 16 + l16) * 64 + (((kkc + quad) ^ sw) * 8));
#pragma unroll
      for (int j = 0; j < 4; ++j) {
        bf16x8 bv = *(const bf16x8*)(Bs + (wc * 64 + j * 16 + l16) * 64 + (((kkc + quad) ^ sw) * 8));
        acc[j] = __builtin_amdgcn_mfma_f32_16x16x32_bf16(av, bv, acc[j], 0, 0, 0);
      }
    }
    __syncthreads();
  }

#pragma unroll
  for (int j = 0; j < 4; ++j)
#pragma unroll
    for (int r = 0; r < 4; ++r) {
      int row = wr * 16 + quad * 4 + r;
      int col = wc * 64 + j * 16 + l16;
      hg[row * 129 + col] = fmaxf(acc[j][r] + bg1s[col], 0.0f);
    }
  __syncthreads();

  {
    int row = tid >> 3, p = tid & 7;
    float s = b2s[p];
    for (int k = 0; k < 128; ++k) s += hg[row * 129 + k] * w2s[k * 8 + p];
    lg[row * 8 + p] = s;
  }
  __syncthreads();

  if (tid < 32) {
    float l[8];
    float m = -1e30f;
#pragma unroll
    for (int e = 0; e < 8; ++e) { l[e] = lg[tid * 8 + e]; m = fmaxf(m, l[e]); }
    float s = 0.0f;
#pragma unroll
    for (int e = 0; e < 8; ++e) { l[e] = expf(l[e] - m); s += l[e]; }
    float inv = 1.0f / s;
    size_t grow = rowBase + tid;
#pragma unroll
    for (int e = 0; e < 8; ++e) {
      float ge = l[e] * inv;
      g[grow * 8 + e] = ge;
      hw[grow * KS + 2048 + e] = f2bf(ge);
    }
#pragma unroll
    for (int z = 0; z < 56; ++z) hw[grow * KS + 2056 + z] = 0;
  }
}

// ---------------- stage 1 (BK=64, swizzled) ----------------

__global__ __launch_bounds__(256) void k_stage1(const USH* __restrict__ xb,
                                                const USH* __restrict__ w1t,
                                                const float* __restrict__ b1,
                                                const float* __restrict__ g,
                                                USH* __restrict__ hw) {
  __shared__ __align__(16) USH As[128 * 64];   // 16KB, swizzled
  __shared__ __align__(16) USH Bs[128 * 64];   // 16KB, swizzled
  __shared__ float gs[128];
  __shared__ float b1s[128];

  int tid = threadIdx.x;
  int wave = tid >> 6, lane = tid & 63;
  int quad = lane >> 4, l16 = lane & 15;
  int sw = l16 & 7;
  int wr = wave >> 1, wc = wave & 1;
  int rowBase = blockIdx.x * 128;
  int colBase = blockIdx.y * 128;
  int e = blockIdx.z;

  if (tid < 128) {
    gs[tid] = g[(size_t)(rowBase + tid) * 8 + e];
    b1s[tid] = b1[e * 256 + colBase + tid];
  }

  const USH* B = w1t + (size_t)e * 65536;

  f32x4 acc[4][4] = {};
  for (int kt = 0; kt < 4; ++kt) {
    int kb = kt * 64;
#pragma unroll
    for (int c = 0; c < 4; ++c) {
      int i = c * 256 + tid;
      int r = i >> 3, c8 = (i & 7) ^ (r & 7);
      gl2lds16(xb + (size_t)(rowBase + r) * 256 + kb + c8 * 8, As + (size_t)i * 8);
      gl2lds16(B + (size_t)(colBase + r) * 256 + kb + c8 * 8, Bs + (size_t)i * 8);
    }
    __syncthreads();
#pragma unroll
    for (int kkc = 0; kkc < 8; kkc += 4) {
      int cs = ((kkc + quad) ^ sw) * 8;
      bf16x8 av[4], bv[4];
#pragma unroll
      for (int i = 0; i < 4; ++i)
        av[i] = *(const bf16x8*)(As + (wr * 64 + i * 16 + l16) * 64 + cs);
#pragma unroll
      for (int j = 0; j < 4; ++j)
        bv[j] = *(const bf16x8*)(Bs + (wc * 64 + j * 16 + l16) * 64 + cs);
#pragma unroll
      for (int i = 0; i < 4; ++i)
#pragma unroll
        for (int j = 0; j < 4; ++j)
          acc[i][j] = __builtin_amdgcn_mfma_f32_16x16x32_bf16(av[i], bv[j], acc[i][j], 0, 0, 0);
    }
    __syncthreads();
  }

#pragma unroll
  for (int i = 0; i < 4; ++i) {
#pragma unroll
    for (int r = 0; r < 4; ++r) {
      int rl = wr * 64 + i * 16 + quad * 4 + r;
      float gg = gs[rl];
      size_t grow = (size_t)(rowBase + rl);
#pragma unroll
      for (int j = 0; j < 4; ++j) {
        int cl = wc * 64 + j * 16 + l16;
        float v = fmaxf(acc[i][j][r] + b1s[cl], 0.0f) * gg;
        hw[grow * KS + e * 256 + colBase + cl] = f2bf(v);
      }
    }
  }
}

// ---------------- stage 2 (64x64 tiles, 1024 blocks, BK=64, swizzled) --------

__global__ __launch_bounds__(256) void k_stage2(const USH* __restrict__ hwm,
                                                const USH* __restrict__ w2t,
                                                float* __restrict__ out) {
  __shared__ __align__(16) USH As[64 * 64];    // 8KB, swizzled
  __shared__ __align__(16) USH Bs[64 * 64];    // 8KB, swizzled

  int tid = threadIdx.x;
  int wave = tid >> 6, lane = tid & 63;
  int quad = lane >> 4, l16 = lane & 15;
  int sw = l16 & 7;
  int rowBase = blockIdx.x * 64;
  int colBase = blockIdx.y * 64;

  f32x4 acc[4] = {};
  for (int kt = 0; kt < 33; ++kt) {
    int kb = kt * 64;
#pragma unroll
    for (int c = 0; c < 2; ++c) {
      int i = c * 256 + tid;
      int r = i >> 3, c8 = (i & 7) ^ (r & 7);
      gl2lds16(hwm + (size_t)(rowBase + r) * KS + kb + c8 * 8, As + (size_t)i * 8);
      gl2lds16(w2t + (size_t)(colBase + r) * KS + kb + c8 * 8, Bs + (size_t)i * 8);
    }
    __syncthreads();
#pragma unroll
    for (int kkc = 0; kkc < 8; kkc += 4) {
      int cs = ((kkc + quad) ^ sw) * 8;
      bf16x8 av = *(const bf16x8*)(As + (wave * 16 + l16) * 64 + cs);
#pragma unroll
      for (int j = 0; j < 4; ++j) {
        bf16x8 bv = *(const bf16x8*)(Bs + (j * 16 + l16) * 64 + cs);
        acc[j] = __builtin_amdgcn_mfma_f32_16x16x32_bf16(av, bv, acc[j], 0, 0, 0);
      }
    }
    __syncthreads();
  }

#pragma unroll
  for (int j = 0; j < 4; ++j)
#pragma unroll
    for (int r = 0; r < 4; ++r) {
      int row = wave * 16 + quad * 4 + r;
      out[(size_t)(rowBase + row) * 256 + colBase + j * 16 + l16] = acc[j][r];
    }
}

// ---------------- launch ----------------

extern "C" void kernel_launch(void* const* d_in, const int* in_sizes, int n_in,
                              void* d_out, int out_size, void* d_ws, size_t ws_size,
                              hipStream_t stream) {
  const float* x   = (const float*)d_in[0];
  const float* Wg1 = (const float*)d_in[1];
  const float* bg1 = (const float*)d_in[2];
  const float* Wg2 = (const float*)d_in[3];
  const float* bg2 = (const float*)d_in[4];
  const float* W1  = (const float*)d_in[5];
  const float* b1  = (const float*)d_in[6];
  const float* W2  = (const float*)d_in[7];
  const float* b2  = (const float*)d_in[8];
  float* out = (float*)d_out;

  char* ws = (char*)d_ws;
  USH*   xb   = (USH*)(ws);
  USH*   w1t  = (USH*)(ws + 8388608);
  USH*   wg1t = (USH*)(ws + 9437184);
  USH*   w2t  = (USH*)(ws + 9502720);
  float* g    = (float*)(ws + 10584064);
  USH*   hw   = (USH*)(ws + 11108352);   // total 80,314,368 B

  hipLaunchKernelGGL(k_prep, dim3(2313), dim3(256), 0, stream,
                     x, Wg1, W1, W2, b2, xb, wg1t, w1t, w2t);
  hipLaunchKernelGGL(k_gate,   dim3(512),       dim3(256), 0, stream, xb, wg1t, bg1, Wg2, bg2, g, hw);
  hipLaunchKernelGGL(k_stage1, dim3(128, 2, 8), dim3(256), 0, stream, xb, w1t, b1, g, hw);
  hipLaunchKernelGGL(k_stage2, dim3(256, 4),    dim3(256), 0, stream, hw, w2t, out);
}